// Round 1
// baseline (294.693 us; speedup 1.0000x reference)
//
#include <hip/hip_runtime.h>

#define B_   8
#define N_   2048
#define H_   512
#define K_   64
#define NROWS 16384   // B_*N_

// ---------------------------------------------------------------------------
// Kernel 1: projections q = x@Wq^T + bq, k = y@Wk^T + bk  (fp32 tiled GEMM)
// Also initializes minT[] to +inf bits.
// Block: 256 threads, 64 rows x 64 out-dims per block, chunks of 64 over H.
// LDS tiles stored transposed [h][row] so inner loop reads are float4.
// ---------------------------------------------------------------------------
__global__ __launch_bounds__(256) void proj_kernel(
    const float* __restrict__ x, const float* __restrict__ y,
    const float* __restrict__ Wq, const float* __restrict__ bq,
    const float* __restrict__ Wk, const float* __restrict__ bk,
    float* __restrict__ qout, float* __restrict__ kout,
    unsigned int* __restrict__ minT)
{
    __shared__ float Xs[64][68];   // [h][row], pad 4 keeps 16B alignment, kills conflicts
    __shared__ float Ws[64][68];   // [h][kk]

    const int tid = threadIdx.x;
    const int blk = blockIdx.x;            // 0..511
    const bool isQ = blk < (NROWS / 64);   // first 256 blocks -> q, rest -> k
    const float* __restrict__ X    = isQ ? x  : y;
    const float* __restrict__ W    = isQ ? Wq : Wk;
    const float* __restrict__ bias = isQ ? bq : bk;
    float* __restrict__ out        = isQ ? qout : kout;
    const int row0 = (isQ ? blk : blk - (NROWS / 64)) * 64;

    // init minT to +inf (covered by blocks 0..63)
    const int fid = blk * 256 + tid;
    if (fid < NROWS) minT[fid] = 0x7f800000u;

    const int lc = tid & 15;    // col-group for staging
    const int lr = tid >> 4;    // row for staging
    const int tx = tid & 15;    // out-dim group (4 kk each)
    const int ty = tid >> 4;    // row group (4 rows each)

    float acc[4][4] = {};

    for (int c = 0; c < 8; ++c) {
        const int h0 = c * 64;
        // stage X chunk transposed
        #pragma unroll
        for (int p = 0; p < 4; ++p) {
            const int r = p * 16 + lr;
            const float4 v = *reinterpret_cast<const float4*>(
                &X[(size_t)(row0 + r) * H_ + h0 + lc * 4]);
            Xs[lc * 4 + 0][r] = v.x; Xs[lc * 4 + 1][r] = v.y;
            Xs[lc * 4 + 2][r] = v.z; Xs[lc * 4 + 3][r] = v.w;
        }
        // stage W chunk transposed (W is [64][512] row-major)
        #pragma unroll
        for (int p = 0; p < 4; ++p) {
            const int r = p * 16 + lr;   // kk index
            const float4 v = *reinterpret_cast<const float4*>(
                &W[(size_t)r * H_ + h0 + lc * 4]);
            Ws[lc * 4 + 0][r] = v.x; Ws[lc * 4 + 1][r] = v.y;
            Ws[lc * 4 + 2][r] = v.z; Ws[lc * 4 + 3][r] = v.w;
        }
        __syncthreads();
        #pragma unroll 16
        for (int h = 0; h < 64; ++h) {
            const float4 xa = *reinterpret_cast<const float4*>(&Xs[h][ty * 4]);
            const float4 wb = *reinterpret_cast<const float4*>(&Ws[h][tx * 4]);
            const float xs[4] = {xa.x, xa.y, xa.z, xa.w};
            const float wsv[4] = {wb.x, wb.y, wb.z, wb.w};
            #pragma unroll
            for (int i = 0; i < 4; ++i)
                #pragma unroll
                for (int j = 0; j < 4; ++j)
                    acc[i][j] = fmaf(xs[i], wsv[j], acc[i][j]);
        }
        __syncthreads();
    }

    const float4 bf = *reinterpret_cast<const float4*>(&bias[tx * 4]);
    #pragma unroll
    for (int i = 0; i < 4; ++i) {
        float4 v;
        v.x = acc[i][0] + bf.x; v.y = acc[i][1] + bf.y;
        v.z = acc[i][2] + bf.z; v.w = acc[i][3] + bf.w;
        *reinterpret_cast<float4*>(
            &out[(size_t)(row0 + ty * 4 + i) * K_ + tx * 4]) = v;
    }
}

// ---------------------------------------------------------------------------
// Kernel 2: minT[b,n] = min over m of (qq_n + kk_m - 2 q_n.k_m)
// Tiled: 64 n x 64 m per block, K=64 fully staged (transposed) in LDS.
// Partial min per block -> atomicMin on uint bits (dist >= 0 so order-safe).
// ---------------------------------------------------------------------------
__global__ __launch_bounds__(256) void dist_kernel(
    const float* __restrict__ q, const float* __restrict__ kmat,
    unsigned int* __restrict__ minT)
{
    __shared__ float Qs[64][68];   // [kdim][n]
    __shared__ float Ks[64][68];   // [kdim][m]
    __shared__ float qqS[64], kkS[64];
    __shared__ float red[64][17];

    const int tid  = threadIdx.x;
    const int b    = blockIdx.z;
    const int nbase = blockIdx.y * 64;
    const int mbase = blockIdx.x * 64;
    const int lc = tid & 15, lr = tid >> 4;

    #pragma unroll
    for (int p = 0; p < 4; ++p) {
        const int r = p * 16 + lr;
        const float4 v = *reinterpret_cast<const float4*>(
            &q[(size_t)(b * N_ + nbase + r) * K_ + lc * 4]);
        Qs[lc * 4 + 0][r] = v.x; Qs[lc * 4 + 1][r] = v.y;
        Qs[lc * 4 + 2][r] = v.z; Qs[lc * 4 + 3][r] = v.w;
        const float4 u = *reinterpret_cast<const float4*>(
            &kmat[(size_t)(b * N_ + mbase + r) * K_ + lc * 4]);
        Ks[lc * 4 + 0][r] = u.x; Ks[lc * 4 + 1][r] = u.y;
        Ks[lc * 4 + 2][r] = u.z; Ks[lc * 4 + 3][r] = u.w;
    }
    __syncthreads();

    if (tid < 64) {
        float s = 0.f;
        #pragma unroll 8
        for (int h = 0; h < 64; ++h) s = fmaf(Qs[h][tid], Qs[h][tid], s);
        qqS[tid] = s;
    } else if (tid < 128) {
        const int t = tid - 64;
        float s = 0.f;
        #pragma unroll 8
        for (int h = 0; h < 64; ++h) s = fmaf(Ks[h][t], Ks[h][t], s);
        kkS[t] = s;
    }
    __syncthreads();

    const int tx = tid & 15;   // m group
    const int ty = tid >> 4;   // n group
    float acc[4][4] = {};
    #pragma unroll 16
    for (int h = 0; h < 64; ++h) {
        const float4 qa = *reinterpret_cast<const float4*>(&Qs[h][ty * 4]);
        const float4 kb = *reinterpret_cast<const float4*>(&Ks[h][tx * 4]);
        const float qs[4] = {qa.x, qa.y, qa.z, qa.w};
        const float ks[4] = {kb.x, kb.y, kb.z, kb.w};
        #pragma unroll
        for (int i = 0; i < 4; ++i)
            #pragma unroll
            for (int j = 0; j < 4; ++j)
                acc[i][j] = fmaf(qs[i], ks[j], acc[i][j]);
    }

    #pragma unroll
    for (int i = 0; i < 4; ++i) {
        const float qq = qqS[ty * 4 + i];
        float best = 1e30f;
        #pragma unroll
        for (int j = 0; j < 4; ++j) {
            const float d = qq + kkS[tx * 4 + j] - 2.0f * acc[i][j];
            best = fminf(best, d);
        }
        red[ty * 4 + i][tx] = best;
    }
    __syncthreads();

    if (tid < 64) {
        float best = red[tid][0];
        #pragma unroll
        for (int j = 1; j < 16; ++j) best = fminf(best, red[tid][j]);
        atomicMin(&minT[b * N_ + nbase + tid], __float_as_uint(best));
    }
}

// ---------------------------------------------------------------------------
// Kernel 3: w[i] = exp(-minDist[i])  (16384 elements)
// ---------------------------------------------------------------------------
__global__ __launch_bounds__(256) void wexp_kernel(
    const unsigned int* __restrict__ minT, float* __restrict__ w)
{
    const int i = blockIdx.x * 256 + threadIdx.x;
    if (i < NROWS) w[i] = expf(-__uint_as_float(minT[i]));
}

// ---------------------------------------------------------------------------
// Kernel 4: out[b,n,m] = w[b,n] * w[b,m]  (134 MB, write-bound, float4 stores)
// ---------------------------------------------------------------------------
__global__ __launch_bounds__(256) void outer_kernel(
    const float* __restrict__ w, float4* __restrict__ out)
{
    const int f = blockIdx.x * 256 + threadIdx.x;  // float4 index, 2^23 total
    const int m4 = f & 511;
    const int n  = (f >> 9) & 2047;
    const int b  = f >> 20;
    const float wn = w[(b << 11) + n];
    const float4 wm = reinterpret_cast<const float4*>(w)[(b << 9) + m4];
    float4 o;
    o.x = wn * wm.x; o.y = wn * wm.y; o.z = wn * wm.z; o.w = wn * wm.w;
    out[f] = o;
}

// ---------------------------------------------------------------------------
extern "C" void kernel_launch(void* const* d_in, const int* in_sizes, int n_in,
                              void* d_out, int out_size, void* d_ws, size_t ws_size,
                              hipStream_t stream)
{
    const float* x  = (const float*)d_in[0];
    const float* y  = (const float*)d_in[1];
    const float* Wq = (const float*)d_in[2];
    const float* bq = (const float*)d_in[3];
    const float* Wk = (const float*)d_in[4];
    const float* bk = (const float*)d_in[5];
    float* out = (float*)d_out;

    float* ws = (float*)d_ws;
    float* q = ws;                                   // 16384*64 = 1,048,576 floats
    float* k = ws + 1048576;                         // 1,048,576 floats
    unsigned int* minT = (unsigned int*)(ws + 2097152);  // 16384 uints
    float* w = ws + 2097152 + 16384;                 // 16384 floats  (~8.5 MB total)

    proj_kernel<<<512, 256, 0, stream>>>(x, y, Wq, bq, Wk, bk, q, k, minT);
    dist_kernel<<<dim3(32, 32, 8), 256, 0, stream>>>(q, k, minT);
    wexp_kernel<<<64, 256, 0, stream>>>(minT, w);
    outer_kernel<<<32768, 256, 0, stream>>>(w, (float4*)out);
}

// Round 2
// 262.552 us; speedup vs baseline: 1.1224x; 1.1224x over previous
//
#include <hip/hip_runtime.h>

#define B_    8
#define N_    2048
#define H_    512
#define K_    64
#define NROWS 16384            // B_*N_
#define RTOT  32768            // q rows + k rows

typedef __attribute__((ext_vector_type(8))) __bf16 bf16x8;
typedef __attribute__((ext_vector_type(4))) float  floatx4;

#define MFMA(a, b, c) __builtin_amdgcn_mfma_f32_16x16x32_bf16((a), (b), (c), 0, 0, 0)

// ---------------------------------------------------------------------------
// Kernel 0: W -> bf16 hi/lo.  Whilo layout: [sel(q=0,k=1)][hi=0,lo=1][64][512]
// ---------------------------------------------------------------------------
__global__ __launch_bounds__(256) void wcvt_kernel(
    const float* __restrict__ Wq, const float* __restrict__ Wk,
    __bf16* __restrict__ Whilo)
{
    const int i = blockIdx.x * 256 + threadIdx.x;     // 0..65535
    const bool isQ = i < 32768;
    const int off = isQ ? i : i - 32768;
    const float f = isQ ? Wq[off] : Wk[off];
    const __bf16 h = (__bf16)f;
    const __bf16 l = (__bf16)(f - (float)h);
    const int base = isQ ? 0 : 65536;
    Whilo[base + off] = h;
    Whilo[base + 32768 + off] = l;
}

// ---------------------------------------------------------------------------
// Kernel 1: projections via MFMA (hi/lo 3-pass), no LDS.
// Block 128 threads = 2 waves; each wave: 32 rows (2 row-tiles of 16).
// Grid 512 blocks over 32768 rows (first 16384 -> q from x, rest -> k from y).
// Emits qh/ql (bf16 hi/lo, [row][64]) and sq[row] = sum(q^2) over the 64 dims.
// A-frag (row=lane&15, k=quad*8..+7) is loaded straight from global as 2 float4
// and split to bf16 hi/lo in registers.
// ---------------------------------------------------------------------------
__global__ __launch_bounds__(128) void proj_kernel(
    const float* __restrict__ x, const float* __restrict__ y,
    const __bf16* __restrict__ Whilo,
    const float* __restrict__ bq, const float* __restrict__ bk,
    __bf16* __restrict__ qh, __bf16* __restrict__ ql,
    float* __restrict__ sq)
{
    const int tid  = threadIdx.x;
    const int wv   = tid >> 6;
    const int lane = tid & 63;
    const int quad = lane >> 4;
    const int l16  = lane & 15;
    const int rowbase = blockIdx.x * 64 + wv * 32;    // global row in [0,32768)
    const bool isQ = rowbase < NROWS;
    const float* __restrict__ X   = isQ ? x : y;
    const int xrow0 = isQ ? rowbase : rowbase - NROWS;
    const __bf16* __restrict__ Whi = Whilo + (isQ ? 0 : 2 * 32768);
    const __bf16* __restrict__ Wlo = Whi + 32768;
    const float* __restrict__ bias = isQ ? bq : bk;

    floatx4 acc[2][4];
    #pragma unroll
    for (int rt = 0; rt < 2; ++rt)
        #pragma unroll
        for (int ot = 0; ot < 4; ++ot)
            acc[rt][ot] = floatx4{0.f, 0.f, 0.f, 0.f};

    for (int it = 0; it < 16; ++it) {
        const int k0 = it * 32 + quad * 8;
        bf16x8 ahi[2], alo[2];
        #pragma unroll
        for (int rt = 0; rt < 2; ++rt) {
            const float4 f0 = *reinterpret_cast<const float4*>(
                &X[(size_t)(xrow0 + rt * 16 + l16) * H_ + k0]);
            const float4 f1 = *reinterpret_cast<const float4*>(
                &X[(size_t)(xrow0 + rt * 16 + l16) * H_ + k0 + 4]);
            const float fv[8] = {f0.x, f0.y, f0.z, f0.w, f1.x, f1.y, f1.z, f1.w};
            #pragma unroll
            for (int j = 0; j < 8; ++j) {
                const __bf16 h = (__bf16)fv[j];
                ahi[rt][j] = h;
                alo[rt][j] = (__bf16)(fv[j] - (float)h);
            }
        }
        bf16x8 bhi[4], blo[4];
        #pragma unroll
        for (int ot = 0; ot < 4; ++ot) {
            const int wrow = ot * 16 + l16;
            bhi[ot] = *reinterpret_cast<const bf16x8*>(&Whi[(size_t)wrow * H_ + k0]);
            blo[ot] = *reinterpret_cast<const bf16x8*>(&Wlo[(size_t)wrow * H_ + k0]);
        }
        #pragma unroll
        for (int rt = 0; rt < 2; ++rt)
            #pragma unroll
            for (int ot = 0; ot < 4; ++ot) {
                acc[rt][ot] = MFMA(ahi[rt], bhi[ot], acc[rt][ot]);
                acc[rt][ot] = MFMA(ahi[rt], blo[ot], acc[rt][ot]);
                acc[rt][ot] = MFMA(alo[rt], bhi[ot], acc[rt][ot]);
            }
    }

    // epilogue: + bias, emit bf16 hi/lo and row sums of squares
    float bv[4];
    #pragma unroll
    for (int ot = 0; ot < 4; ++ot) bv[ot] = bias[ot * 16 + l16];

    #pragma unroll
    for (int rt = 0; rt < 2; ++rt) {
        float ss[4] = {0.f, 0.f, 0.f, 0.f};
        #pragma unroll
        for (int ot = 0; ot < 4; ++ot)
            #pragma unroll
            for (int r = 0; r < 4; ++r) {
                const float qv = acc[rt][ot][r] + bv[ot];
                acc[rt][ot][r] = qv;
                ss[r] = fmaf(qv, qv, ss[r]);
            }
        #pragma unroll
        for (int off = 1; off < 16; off <<= 1)
            #pragma unroll
            for (int r = 0; r < 4; ++r)
                ss[r] += __shfl_xor(ss[r], off);
        const int row0 = rowbase + rt * 16 + quad * 4;   // + r
        if (l16 == 0) {
            #pragma unroll
            for (int r = 0; r < 4; ++r) sq[row0 + r] = ss[r];
        }
        #pragma unroll
        for (int ot = 0; ot < 4; ++ot)
            #pragma unroll
            for (int r = 0; r < 4; ++r) {
                const size_t idx = (size_t)(row0 + r) * K_ + ot * 16 + l16;
                const float qv = acc[rt][ot][r];
                const __bf16 h = (__bf16)qv;
                qh[idx] = h;
                ql[idx] = (__bf16)(qv - (float)h);
            }
    }
}

// ---------------------------------------------------------------------------
// Kernel 2: w[b,n] = exp(-min_m dist(n,m)) via MFMA, no LDS, no atomics.
// Block 128 = 2 waves; wave handles 16 n-rows, sweeps all 2048 m in 16-subtiles.
// Q frags stay in registers; K frags read from global (L2: 512 KB/batch).
// dist' = kk[m] - 2*q.k is min-reduced; qq added once at the end.
// ---------------------------------------------------------------------------
__global__ __launch_bounds__(128) void dist_kernel(
    const __bf16* __restrict__ qh, const __bf16* __restrict__ ql,
    const float* __restrict__ sq, float* __restrict__ wout)
{
    const int tid  = threadIdx.x;
    const int wv   = tid >> 6;
    const int lane = tid & 63;
    const int quad = lane >> 4;
    const int l16  = lane & 15;
    const int blk  = blockIdx.x;          // 512: b = blk>>6, ntile = blk&63
    const int b    = blk >> 6;
    const int nrow = (blk & 63) * 32 + wv * 16;      // within batch
    const size_t qrow = (size_t)(b * N_ + nrow + l16);

    const bf16x8 ahi0 = *reinterpret_cast<const bf16x8*>(&qh[qrow * K_ + quad * 8]);
    const bf16x8 ahi1 = *reinterpret_cast<const bf16x8*>(&qh[qrow * K_ + 32 + quad * 8]);
    const bf16x8 alo0 = *reinterpret_cast<const bf16x8*>(&ql[qrow * K_ + quad * 8]);
    const bf16x8 alo1 = *reinterpret_cast<const bf16x8*>(&ql[qrow * K_ + 32 + quad * 8]);

    const __bf16* __restrict__ kh = qh + (size_t)NROWS * K_;
    const __bf16* __restrict__ kl = ql + (size_t)NROWS * K_;
    const float*  __restrict__ kk = sq + NROWS;

    floatx4 runmin = floatx4{1e30f, 1e30f, 1e30f, 1e30f};

    #pragma unroll 2
    for (int ms = 0; ms < 128; ++ms) {
        const size_t krow = (size_t)(b * N_ + ms * 16 + l16);
        const bf16x8 bh0 = *reinterpret_cast<const bf16x8*>(&kh[krow * K_ + quad * 8]);
        const bf16x8 bh1 = *reinterpret_cast<const bf16x8*>(&kh[krow * K_ + 32 + quad * 8]);
        const bf16x8 bl0 = *reinterpret_cast<const bf16x8*>(&kl[krow * K_ + quad * 8]);
        const bf16x8 bl1 = *reinterpret_cast<const bf16x8*>(&kl[krow * K_ + 32 + quad * 8]);
        const float kkv = kk[b * N_ + ms * 16 + l16];

        floatx4 acc = floatx4{0.f, 0.f, 0.f, 0.f};
        acc = MFMA(ahi0, bh0, acc);
        acc = MFMA(ahi1, bh1, acc);
        acc = MFMA(ahi0, bl0, acc);
        acc = MFMA(ahi1, bl1, acc);
        acc = MFMA(alo0, bh0, acc);
        acc = MFMA(alo1, bh1, acc);

        #pragma unroll
        for (int r = 0; r < 4; ++r) {
            const float d = fmaf(-2.f, acc[r], kkv);
            runmin[r] = fminf(runmin[r], d);
        }
    }

    #pragma unroll
    for (int off = 1; off < 16; off <<= 1)
        #pragma unroll
        for (int r = 0; r < 4; ++r)
            runmin[r] = fminf(runmin[r], __shfl_xor(runmin[r], off));

    if (l16 == 0) {
        #pragma unroll
        for (int r = 0; r < 4; ++r) {
            const int row = nrow + quad * 4 + r;
            const float d = runmin[r] + sq[b * N_ + row];
            wout[b * N_ + row] = expf(-d);
        }
    }
}

// ---------------------------------------------------------------------------
// Kernel 3: out[b,n,m] = w[b,n] * w[b,m]  (134 MB, write-bound, float4 stores)
// ---------------------------------------------------------------------------
__global__ __launch_bounds__(256) void outer_kernel(
    const float* __restrict__ w, float4* __restrict__ out)
{
    const int f = blockIdx.x * 256 + threadIdx.x;  // float4 index, 2^23 total
    const int m4 = f & 511;
    const int n  = (f >> 9) & 2047;
    const int b  = f >> 20;
    const float wn = w[(b << 11) + n];
    const float4 wm = reinterpret_cast<const float4*>(w)[(b << 9) + m4];
    float4 o;
    o.x = wn * wm.x; o.y = wn * wm.y; o.z = wn * wm.z; o.w = wn * wm.w;
    out[f] = o;
}

// ---------------------------------------------------------------------------
extern "C" void kernel_launch(void* const* d_in, const int* in_sizes, int n_in,
                              void* d_out, int out_size, void* d_ws, size_t ws_size,
                              hipStream_t stream)
{
    const float* x  = (const float*)d_in[0];
    const float* y  = (const float*)d_in[1];
    const float* Wq = (const float*)d_in[2];
    const float* bq = (const float*)d_in[3];
    const float* Wk = (const float*)d_in[4];
    const float* bk = (const float*)d_in[5];
    float* out = (float*)d_out;

    char* ws = (char*)d_ws;
    __bf16* qh    = (__bf16*)ws;                          // RTOT*K_ = 2M elems, 4 MB
    __bf16* ql    = (__bf16*)(ws + 4194304);              // 4 MB
    float*  sq    = (float*)(ws + 8388608);               // 32768 floats, 128 KB
    __bf16* Whilo = (__bf16*)(ws + 8519680);              // 4*32768 elems, 256 KB
    float*  w     = (float*)(ws + 8781824);               // 16384 floats, 64 KB

    wcvt_kernel<<<256, 256, 0, stream>>>(Wq, Wk, Whilo);
    proj_kernel<<<512, 128, 0, stream>>>(x, y, Whilo, bq, bk, qh, ql, sq);
    dist_kernel<<<512, 128, 0, stream>>>(qh, ql, sq, w);
    outer_kernel<<<32768, 256, 0, stream>>>(w, (float4*)out);
}